// Round 2
// baseline (220.386 us; speedup 1.0000x reference)
//
#include <hip/hip_runtime.h>
#include <hip/hip_bf16.h>
#include <stdint.h>

#define B_ 2
#define T_ 2048
#define D_ 1024
#define H_ 16
#define DEPTH 64

typedef unsigned short u16;
typedef unsigned int u32;
typedef short bf16x8 __attribute__((ext_vector_type(8)));
typedef short bf16x4 __attribute__((ext_vector_type(4)));
typedef float f32x4 __attribute__((ext_vector_type(4)));
typedef float f32x16 __attribute__((ext_vector_type(16)));

#define MFMA16(a, b, c) __builtin_amdgcn_mfma_f32_16x16x32_bf16(a, b, c, 0, 0, 0)
#define MFMA32(a, b, c) __builtin_amdgcn_mfma_f32_32x32x16_bf16(a, b, c, 0, 0, 0)

// raw v_exp_f32 (1 VALU inst) -- OCML exp2f costs ~10+ insts in fixups we
// don't need (args in [-6.2e9, ~2]; result rounded to bf16 afterwards anyway)
#if __has_builtin(__builtin_amdgcn_exp2f)
#define EXP2(x) __builtin_amdgcn_exp2f(x)
#else
#define EXP2(x) __expf((x) * 0.6931471805599453f)
#endif

// async global->LDS, 16B per lane; LDS dest = wave-uniform base + lane*16
#define GLOAD_LDS(g, l)                                                      \
    __builtin_amdgcn_global_load_lds(                                        \
        (__attribute__((address_space(1))) void*)(g),                        \
        (__attribute__((address_space(3))) void*)(l), 16, 0, 0)

__device__ __forceinline__ float bf2f(u32 u) {
    union { u32 i; float f; } x; x.i = u << 16; return x.f;
}
__device__ __forceinline__ u16 f2bf(float f) {
    union { float f; u32 i; } x; x.f = f;
    u32 r = x.i + 0x7fffu + ((x.i >> 16) & 1u);
    return (u16)(r >> 16);
}
__device__ __forceinline__ uint2 pk4(float4 f) {
    return make_uint2((u32)f2bf(f.x) | ((u32)f2bf(f.y) << 16),
                      (u32)f2bf(f.z) | ((u32)f2bf(f.w) << 16));
}
// 1-inst packed f32->bf16x2 (RNE); compiler cannot derive this from bit-ops
__device__ __forceinline__ u32 cvtpk(float lo, float hi) {
    u32 r;
    asm("v_cvt_pk_bf16_f32 %0, %1, %2" : "=v"(r) : "v"(lo), "v"(hi));
    return r;
}
__device__ __forceinline__ bf16x8 pk_frag(u32 a, u32 b, u32 c, u32 d) {
    union { u32 u[4]; bf16x8 v; } x;
    x.u[0] = a; x.u[1] = b; x.u[2] = c; x.u[3] = d;
    return x.v;
}
__device__ __forceinline__ bf16x8 cat44(bf16x4 a, bf16x4 b) {
    bf16x8 r;
    r[0] = a[0]; r[1] = a[1]; r[2] = a[2]; r[3] = a[3];
    r[4] = b[0]; r[5] = b[1]; r[6] = b[2]; r[7] = b[3];
    return r;
}
__device__ __forceinline__ f32x16 zero16() {
    f32x16 z;
    #pragma unroll
    for (int i = 0; i < 16; ++i) z[i] = 0.f;
    return z;
}

// ---------------------------------------------------------------------------
// fp32 -> bf16 convert: X (q,k,v: 4M each) and W (wq,wk,wv: 1M each)
// ---------------------------------------------------------------------------
__global__ __launch_bounds__(256) void conv_kernel(
    const float* __restrict__ s0, const float* __restrict__ s1, const float* __restrict__ s2,
    const float* __restrict__ s3, const float* __restrict__ s4, const float* __restrict__ s5,
    u16* __restrict__ xbf, u16* __restrict__ wbf)
{
    const int z = blockIdx.y;
    const float* src = (z == 0) ? s0 : (z == 1) ? s1 : (z == 2) ? s2
                     : (z == 3) ? s3 : (z == 4) ? s4 : s5;
    u16* dst = (z < 3) ? (xbf + (size_t)z * 4194304) : (wbf + (size_t)(z - 3) * 1048576);
    const size_t nel = (z < 3) ? 4194304u : 1048576u;
    for (size_t i = ((size_t)blockIdx.x * 256 + threadIdx.x) * 8; i < nel;
         i += (size_t)gridDim.x * 2048) {
        float4 a = *(const float4*)(src + i);
        float4 b = *(const float4*)(src + i + 4);
        uint2 lo = pk4(a), hi = pk4(b);
        *(uint4*)(dst + i) = make_uint4(lo.x, lo.y, hi.x, hi.y);
    }
}

// ---------------------------------------------------------------------------
// Projection: bf16 X @ W^T + bias. 128x128 tile, BK=64, global_load_lds
// width-16, XOR chunk swizzle, single-buffered (3 blocks/CU beats dbuf's 2).
// Q/K head-split [h*B+b][t][64]; V transposed [h*B+b][64][T].
// ---------------------------------------------------------------------------
__global__ __launch_bounds__(256, 3) void proj_mfma(
    const u16* __restrict__ xbf, const u16* __restrict__ wbf,
    const float* __restrict__ bq, const float* __restrict__ bk, const float* __restrict__ bv,
    u16* __restrict__ qh, u16* __restrict__ kh, u16* __restrict__ vt)
{
    __shared__ __attribute__((aligned(16))) u16 As[128 * 64];
    __shared__ __attribute__((aligned(16))) u16 Bs[128 * 64];

    const int z = blockIdx.z;
    const u16* A = xbf + (size_t)z * 4194304;
    const u16* W = wbf + (size_t)z * 1048576;
    const float* bias = (z == 0) ? bq : (z == 1) ? bk : bv;

    const int tid = threadIdx.x, w = tid >> 6, lane = tid & 63;
    const int quad = lane >> 4, l16 = lane & 15;
    const int m0 = blockIdx.y * 128, n0 = blockIdx.x * 128;
    const int wm = (w & 1) * 64, wn = (w >> 1) * 64;
    const int srow = lane >> 3;                 // 0..7
    const int schunk = (lane & 7) ^ srow;       // xor-swizzled source chunk

    f32x4 acc[4][4];
    #pragma unroll
    for (int mi = 0; mi < 4; ++mi)
        #pragma unroll
        for (int ni = 0; ni < 4; ++ni) acc[mi][ni] = (f32x4){0.f, 0.f, 0.f, 0.f};

    const size_t ar = (size_t)(m0 + 32 * w + srow);
    const size_t br = (size_t)(n0 + 32 * w + srow);

    for (int k0 = 0; k0 < D_; k0 += 64) {
        __syncthreads();
        #pragma unroll
        for (int i = 0; i < 4; ++i) {
            GLOAD_LDS(A + (ar + 8 * i) * D_ + k0 + schunk * 8, &As[(32 * w + 8 * i) * 64]);
            GLOAD_LDS(W + (br + 8 * i) * D_ + k0 + schunk * 8, &Bs[(32 * w + 8 * i) * 64]);
        }
        __syncthreads();

        #pragma unroll
        for (int kg = 0; kg < 2; ++kg) {
            const int ch = ((4 * kg + quad) ^ (l16 & 7)) * 8;
            bf16x8 af[4], bf[4];
            #pragma unroll
            for (int mi = 0; mi < 4; ++mi)
                af[mi] = *(const bf16x8*)&As[(wm + 16 * mi + l16) * 64 + ch];
            #pragma unroll
            for (int ni = 0; ni < 4; ++ni)
                bf[ni] = *(const bf16x8*)&Bs[(wn + 16 * ni + l16) * 64 + ch];
            #pragma unroll
            for (int mi = 0; mi < 4; ++mi)
                #pragma unroll
                for (int ni = 0; ni < 4; ++ni)
                    acc[mi][ni] = MFMA16(af[mi], bf[ni], acc[mi][ni]);
        }
    }

    float bl[4];
    #pragma unroll
    for (int ni = 0; ni < 4; ++ni) bl[ni] = bias[n0 + wn + ni * 16 + l16];

    #pragma unroll
    for (int mi = 0; mi < 4; ++mi) {
        const int mb = m0 + wm + mi * 16 + quad * 4;
        #pragma unroll
        for (int ni = 0; ni < 4; ++ni) {
            const int nn = n0 + wn + ni * 16 + l16;
            const int head = nn >> 6, d = nn & 63;
            if (z < 2) {
                u16* outp = (z == 0) ? qh : kh;
                #pragma unroll
                for (int r = 0; r < 4; ++r) {
                    const int m = mb + r;
                    const int b = m >> 11, t = m & (T_ - 1);
                    outp[((size_t)(head * B_ + b) * T_ + t) * DEPTH + d] =
                        f2bf(acc[mi][ni][r] + bl[ni]);
                }
            } else {
                const int b = mb >> 11, t = mb & (T_ - 1);
                float4 f = make_float4(acc[mi][ni][0] + bl[ni], acc[mi][ni][1] + bl[ni],
                                       acc[mi][ni][2] + bl[ni], acc[mi][ni][3] + bl[ni]);
                *(uint2*)(vt + ((size_t)(head * B_ + b) * DEPTH + d) * T_ + t) = pk4(f);
            }
        }
    }
}

// ---------------------------------------------------------------------------
// Flash attention, 32x32 swapped S^T, fixed-max softmax, SPLIT-K over 2 key
// halves. One wave = 32 queries. In-register P: the PV k-slot->key mapping
// key(kc,h,j) = 16kc + 4h + (j&3) + 8(j>>2) makes the S^T output registers
// exactly the PV A-fragments -- no P LDS round-trip, no cross-lane moves.
// V pays 2x ds_read_b64 per fragment (same bytes). K/V double-buffered with
// stage(next) -> compute(cur) -> barrier (T3 minimum 2-phase): global loads
// fly under compute. cvt_pk_bf16_f32 packs P (1 inst / 2 vals).
// Mask quirk: row n uses mask[n / H]. V pre-transposed [n][64][T].
// ---------------------------------------------------------------------------
__global__ __launch_bounds__(256, 4) void attn_kernel(
    const u16* __restrict__ qh, const u16* __restrict__ kh, const u16* __restrict__ vt,
    const int* __restrict__ maskp, const int* __restrict__ causp,
    u16* __restrict__ po, float* __restrict__ pl)
{
    __shared__ __attribute__((aligned(16))) u16 Ks[2][64 * 64];   // [key][depth] swizzled
    __shared__ __attribute__((aligned(16))) u16 Vs[2][64 * 64];   // [depth][key] swizzled
    __shared__ __attribute__((aligned(16))) float padf[1024];     // mask*PAD, this half

    const int n  = blockIdx.y;          // head*B + b
    const int qt = blockIdx.x;          // 128-query tile
    const int kk = blockIdx.z;          // key half
    const int kbase = kk * 1024;
    const int head = n >> 1, bi = n & 1;
    const int mrow = n >> 4;            // n / H  (reference repeat quirk)
    const int caus = causp[0];

    const int tid  = threadIdx.x;
    const int w    = tid >> 6, lane = tid & 63;
    const int l32  = lane & 31, h = lane >> 5;
    const size_t base  = (size_t)n * T_ * DEPTH;
    const size_t vbase = (size_t)n * DEPTH * T_;
    const size_t elems = (size_t)B_ * T_ * D_;

    const float C1  = 0.18033688011112042f;   // (1/8) * log2(e)
    const float PL2 = -6.2e9f;                // exp2 -> 0

    // precompute pad row for this key half (once per block)
    {
        const int i0 = tid * 4;
        int4 m = *(const int4*)(maskp + (size_t)mrow * T_ + kbase + i0);
        padf[i0 + 0] = (float)m.x * PL2; padf[i0 + 1] = (float)m.y * PL2;
        padf[i0 + 2] = (float)m.z * PL2; padf[i0 + 3] = (float)m.w * PL2;
    }

    // Q fragments (B operand, 32x32x16): lane holds Q[q = l32][c*16 + h*8 + j]
    const int qg = qt * 128 + w * 32 + l32;
    bf16x8 aq[4];
    #pragma unroll
    for (int c = 0; c < 4; ++c)
        aq[c] = *(const bf16x8*)(qh + base + (size_t)qg * DEPTH + c * 16 + h * 8);

    f32x16 O0 = zero16(), O1 = zero16();   // O[q][d], d halves 0..31 / 32..63
    float lp = 0.f;

    // staging addresses: wave w stages tile rows w*16..w*16+15
    const int g_row = w * 16 + (lane >> 3);           // tile row this lane feeds
    const int g_ch  = (lane & 7) ^ ((lane >> 3) & 7); // swizzled source chunk
    const u16* ksrc = kh + base + (size_t)g_row * DEPTH + g_ch * 8;
    const u16* vsrc = vt + vbase + (size_t)g_row * T_ + g_ch * 8;

#define STAGE(bf_, t0_)                                                           \
    do {                                                                          \
        GLOAD_LDS(ksrc + (size_t)(t0_) * DEPTH,       &Ks[bf_][(w * 16) * 64]);   \
        GLOAD_LDS(ksrc + (size_t)((t0_) + 8) * DEPTH, &Ks[bf_][(w * 16 + 8) * 64]); \
        GLOAD_LDS(vsrc + (t0_),                       &Vs[bf_][(w * 16) * 64]);   \
        GLOAD_LDS(vsrc + (size_t)8 * T_ + (t0_),      &Vs[bf_][(w * 16 + 8) * 64]); \
    } while (0)

    STAGE(0, kbase);
    __syncthreads();   // drains prologue loads; also covers padf

    for (int it = 0; it < 16; ++it) {
        const int cur = it & 1;
        if (it < 15) STAGE(cur ^ 1, kbase + (it + 1) * 64);  // fly under compute

        const int lt0 = it * 64;
        bf16x8 pa[2][2];   // [kb][kc] PV A-fragments, built in-register
        #pragma unroll
        for (int kb = 0; kb < 2; ++kb) {
            // S^T = K * Q^T over depth 64: D[key][q], q = l32 (in-lane)
            const int krow = kb * 32 + l32;
            const u16* krp = &Ks[cur][krow * 64];
            const int ksw = krow & 7;
            f32x16 st = zero16();
            #pragma unroll
            for (int c = 0; c < 4; ++c) {
                bf16x8 kf = *(const bf16x8*)(krp + (((c * 2 + h) ^ ksw) * 8));
                st = MFMA32(kf, aq[c], st);
            }
            // softmax: e[r] = exp2(S*C1 + pad), key(r) = (r&3) + 8(r>>2) + 4h
            u32 pk[8];
            #pragma unroll
            for (int g = 0; g < 4; ++g) {
                f32x4 pv = *(const f32x4*)&padf[lt0 + kb * 32 + g * 8 + h * 4];
                #pragma unroll
                for (int m2 = 0; m2 < 2; ++m2) {
                    const int r0 = g * 4 + m2 * 2;
                    float v0 = fmaf(st[r0],     C1, pv[m2 * 2]);
                    float v1 = fmaf(st[r0 + 1], C1, pv[m2 * 2 + 1]);
                    if (caus) {
                        const int kg = kbase + lt0 + kb * 32 + g * 8 + h * 4 + m2 * 2;
                        if (kg     > qg) v0 = PL2;
                        if (kg + 1 > qg) v1 = PL2;
                    }
                    const float e0 = EXP2(v0), e1 = EXP2(v1);
                    lp += e0 + e1;
                    pk[g * 2 + m2] = cvtpk(e0, e1);
                }
            }
            pa[kb][0] = pk_frag(pk[0], pk[1], pk[2], pk[3]);  // e[0..7]
            pa[kb][1] = pk_frag(pk[4], pk[5], pk[6], pk[7]);  // e[8..15]
        }

        // PV: O[q][d] += P * V with k-slot key = kb*32 + kc*16 + 4h + (j&3) + 8(j>>2)
        #pragma unroll
        for (int dblk = 0; dblk < 2; ++dblk) {
            const int d = dblk * 32 + l32;
            const u16* vrp = &Vs[cur][d * 64 + 4 * h];
            const int vsw = d & 7;
            #pragma unroll
            for (int kb = 0; kb < 2; ++kb)
                #pragma unroll
                for (int kc = 0; kc < 2; ++kc) {
                    const int p0 = (kb * 4 + kc * 2) ^ vsw;   // swizzled chunk
                    bf16x4 vlo = *(const bf16x4*)(vrp + p0 * 8);        // keys +0..3
                    bf16x4 vhi = *(const bf16x4*)(vrp + (p0 ^ 1) * 8);  // keys +8..11
                    bf16x8 vf = cat44(vlo, vhi);
                    if (dblk == 0) O0 = MFMA32(pa[kb][kc], vf, O0);
                    else           O1 = MFMA32(pa[kb][kc], vf, O1);
                }
        }
        __syncthreads();  // drains next-tile loads (issued pre-compute) + LDS reuse
    }
#undef STAGE

    // fold l across halves; write partial l (query = l32)
    lp += __shfl_xor(lp, 32, 64);
    u16* pop = po + (size_t)kk * elems;
    float* plp = pl + (size_t)kk * 32 * T_;
    if (lane < 32)
        plp[(size_t)n * T_ + qt * 128 + w * 32 + l32] = lp;

    // write partial O (bf16, un-normalized): row r -> query (r&3)+8(r>>2)+4h
    #pragma unroll
    for (int r = 0; r < 16; ++r) {
        const int q = qt * 128 + w * 32 + (r & 3) + 8 * (r >> 2) + 4 * h;
        const size_t rb = ((size_t)bi * T_ + q) * D_ + head * DEPTH + l32;
        pop[rb]      = f2bf(O0[r]);
        pop[rb + 32] = f2bf(O1[r]);
    }
}

// ---------------------------------------------------------------------------
// Fused combine + residual + LayerNorm: x = (po0+po1)/(l0+l1) + q; LN over D.
// ---------------------------------------------------------------------------
__global__ __launch_bounds__(256) void fuse_ln(
    const u16* __restrict__ po, const float* __restrict__ pl,
    const float* __restrict__ qin,
    const float* __restrict__ gamma, const float* __restrict__ beta,
    float* __restrict__ out)
{
    const int row = blockIdx.x;           // bi*T + t
    const int bi = row >> 11, t = row & (T_ - 1);
    const int tid = threadIdx.x;
    const size_t elems = (size_t)B_ * T_ * D_;

    const int head = tid >> 4;
    const size_t li = (size_t)(head * B_ + bi) * T_ + t;
    const float l = pl[li] + pl[32 * T_ + li];
    const float inv = 1.0f / fmaxf(l, 1e-30f);

    const size_t basei = (size_t)row * D_ + (tid << 2);
    uint2 a = *(const uint2*)(po + basei);
    uint2 b = *(const uint2*)(po + elems + basei);
    float4 qv = *(const float4*)(qin + basei);
    float x[4];
    x[0] = (bf2f(a.x & 0xffffu) + bf2f(b.x & 0xffffu)) * inv + qv.x;
    x[1] = (bf2f(a.x >> 16)     + bf2f(b.x >> 16))     * inv + qv.y;
    x[2] = (bf2f(a.y & 0xffffu) + bf2f(b.y & 0xffffu)) * inv + qv.z;
    x[3] = (bf2f(a.y >> 16)     + bf2f(b.y >> 16))     * inv + qv.w;

    float s  = x[0] + x[1] + x[2] + x[3];
    float s2 = x[0]*x[0] + x[1]*x[1] + x[2]*x[2] + x[3]*x[3];
    #pragma unroll
    for (int off = 1; off < 64; off <<= 1) {
        s  += __shfl_xor(s, off, 64);
        s2 += __shfl_xor(s2, off, 64);
    }
    __shared__ float rs[4], rs2[4];
    const int wid = tid >> 6;
    if ((tid & 63) == 0) { rs[wid] = s; rs2[wid] = s2; }
    __syncthreads();
    s  = rs[0] + rs[1] + rs[2] + rs[3];
    s2 = rs2[0] + rs2[1] + rs2[2] + rs2[3];
    const float mean = s * (1.0f / (float)D_);
    const float var  = s2 * (1.0f / (float)D_) - mean * mean;
    const float rstd = rsqrtf(var + 1e-5f);
    float4 g = *(const float4*)(gamma + (tid << 2));
    float4 bb = *(const float4*)(beta + (tid << 2));
    float4 r;
    r.x = (x[0] - mean) * rstd * g.x + bb.x;
    r.y = (x[1] - mean) * rstd * g.y + bb.y;
    r.z = (x[2] - mean) * rstd * g.z + bb.z;
    r.w = (x[3] - mean) * rstd * g.w + bb.w;
    *(float4*)(out + basei) = r;
}

extern "C" void kernel_launch(void* const* d_in, const int* in_sizes, int n_in,
                              void* d_out, int out_size, void* d_ws, size_t ws_size,
                              hipStream_t stream)
{
    (void)in_sizes; (void)n_in; (void)out_size; (void)ws_size;
    const float* q    = (const float*)d_in[0];
    const float* k    = (const float*)d_in[1];
    const float* v    = (const float*)d_in[2];
    const int* mask = (const int*)d_in[3];
    const int* caus = (const int*)d_in[4];
    /* d_in[5] = edge_fea (unused) */
    const float* wq = (const float*)d_in[6];
    const float* bq = (const float*)d_in[7];
    const float* wk = (const float*)d_in[8];
    const float* bk = (const float*)d_in[9];
    const float* wv = (const float*)d_in[10];
    const float* bv = (const float*)d_in[11];
    const float* gamma = (const float*)d_in[12];
    const float* beta  = (const float*)d_in[13];
    float* out = (float*)d_out;

    const size_t elems = (size_t)B_ * T_ * D_;   // 4,194,304
    u16* qh  = (u16*)d_ws;
    u16* kh  = qh + elems;
    u16* vt  = kh + elems;                       // transposed V [n][64][T]
    u16* xbf = vt + elems;                       // bf16 X, 3 tensors (dead after proj)
    u16* wbf = xbf + 3 * elems;                  // bf16 W, 3 tensors
    // po/pl reuse the xbf region (proj finished before attn writes them):
    u16* po   = xbf;                             // 2 x elems bf16 partial O
    float* pl = (float*)(po + 2 * elems);        // 2 x 32 x T fp32 partial l

    conv_kernel<<<dim3(512, 6), 256, 0, stream>>>(q, k, v, wq, wk, wv, xbf, wbf);
    proj_mfma<<<dim3(8, 32, 3), 256, 0, stream>>>(xbf, wbf, bq, bk, bv, qh, kh, vt);

    dim3 agrid(T_ / 128, H_ * B_, 2);            // 16 x 32 x 2 = 1024 blocks
    attn_kernel<<<agrid, 256, 0, stream>>>(qh, kh, vt, mask, caus, po, pl);

    fuse_ln<<<B_ * T_, 256, 0, stream>>>(po, pl, q, gamma, beta, out);
}

// Round 3
// 214.604 us; speedup vs baseline: 1.0269x; 1.0269x over previous
//
#include <hip/hip_runtime.h>
#include <hip/hip_bf16.h>
#include <stdint.h>

#define B_ 2
#define T_ 2048
#define D_ 1024
#define H_ 16
#define DEPTH 64

typedef unsigned short u16;
typedef unsigned int u32;
typedef short bf16x8 __attribute__((ext_vector_type(8)));
typedef float f32x4 __attribute__((ext_vector_type(4)));
typedef float f32x16 __attribute__((ext_vector_type(16)));

#define MFMA16(a, b, c) __builtin_amdgcn_mfma_f32_16x16x32_bf16(a, b, c, 0, 0, 0)
#define MFMA32(a, b, c) __builtin_amdgcn_mfma_f32_32x32x16_bf16(a, b, c, 0, 0, 0)

// raw v_exp_f32 (1 VALU inst) -- OCML exp2f costs ~10+ insts in fixups we
// don't need (args in [-6.2e9, ~2]; result rounded to bf16 afterwards anyway)
#if __has_builtin(__builtin_amdgcn_exp2f)
#define EXP2(x) __builtin_amdgcn_exp2f(x)
#else
#define EXP2(x) __expf((x) * 0.6931471805599453f)
#endif

// async global->LDS, 16B per lane; LDS dest = wave-uniform base + lane*16
#define GLOAD_LDS(g, l)                                                      \
    __builtin_amdgcn_global_load_lds(                                        \
        (__attribute__((address_space(1))) void*)(g),                        \
        (__attribute__((address_space(3))) void*)(l), 16, 0, 0)

// counted waits / raw barrier with compiler memory fences (T4)
#define WAITVM(n) asm volatile("s_waitcnt vmcnt(" #n ")" ::: "memory")
#define BARRIER()                                                            \
    do {                                                                     \
        asm volatile("" ::: "memory");                                       \
        __builtin_amdgcn_s_barrier();                                        \
        asm volatile("" ::: "memory");                                       \
    } while (0)

__device__ __forceinline__ float bf2f(u32 u) {
    union { u32 i; float f; } x; x.i = u << 16; return x.f;
}
__device__ __forceinline__ u16 f2bf(float f) {
    union { float f; u32 i; } x; x.f = f;
    u32 r = x.i + 0x7fffu + ((x.i >> 16) & 1u);
    return (u16)(r >> 16);
}
__device__ __forceinline__ uint2 pk4(float4 f) {
    return make_uint2((u32)f2bf(f.x) | ((u32)f2bf(f.y) << 16),
                      (u32)f2bf(f.z) | ((u32)f2bf(f.w) << 16));
}
// 1-inst packed f32->bf16x2 (RNE); compiler cannot derive this from bit-ops
__device__ __forceinline__ u32 cvtpk(float lo, float hi) {
    u32 r;
    asm("v_cvt_pk_bf16_f32 %0, %1, %2" : "=v"(r) : "v"(lo), "v"(hi));
    return r;
}
__device__ __forceinline__ bf16x8 pk_frag(u32 a, u32 b, u32 c, u32 d) {
    union { u32 u[4]; bf16x8 v; } x;
    x.u[0] = a; x.u[1] = b; x.u[2] = c; x.u[3] = d;
    return x.v;
}
__device__ __forceinline__ f32x16 zero16() {
    f32x16 z;
    #pragma unroll
    for (int i = 0; i < 16; ++i) z[i] = 0.f;
    return z;
}

// ---------------------------------------------------------------------------
// fp32 -> bf16 convert: X (q,k,v: 4M each) and W (wq,wk,wv: 1M each)
// ---------------------------------------------------------------------------
__global__ __launch_bounds__(256) void conv_kernel(
    const float* __restrict__ s0, const float* __restrict__ s1, const float* __restrict__ s2,
    const float* __restrict__ s3, const float* __restrict__ s4, const float* __restrict__ s5,
    u16* __restrict__ xbf, u16* __restrict__ wbf)
{
    const int z = blockIdx.y;
    const float* src = (z == 0) ? s0 : (z == 1) ? s1 : (z == 2) ? s2
                     : (z == 3) ? s3 : (z == 4) ? s4 : s5;
    u16* dst = (z < 3) ? (xbf + (size_t)z * 4194304) : (wbf + (size_t)(z - 3) * 1048576);
    const size_t nel = (z < 3) ? 4194304u : 1048576u;
    for (size_t i = ((size_t)blockIdx.x * 256 + threadIdx.x) * 8; i < nel;
         i += (size_t)gridDim.x * 2048) {
        float4 a = *(const float4*)(src + i);
        float4 b = *(const float4*)(src + i + 4);
        uint2 lo = pk4(a), hi = pk4(b);
        *(uint4*)(dst + i) = make_uint4(lo.x, lo.y, hi.x, hi.y);
    }
}

// ---------------------------------------------------------------------------
// Projection: bf16 X @ W^T + bias. 128x128 tile, BK=64, global_load_lds
// width-16, XOR chunk swizzle, single-buffered (3 blocks/CU beats dbuf's 2).
// Q/K head-split [h*B+b][t][64]; V transposed [h*B+b][64][T'] with the key
// axis bit-2<->bit-3 permuted within each 16 (so attn PV V-fragments are one
// contiguous b128 chunk: keys {0-3,8-11}+4h of each 16-group land adjacent).
// ---------------------------------------------------------------------------
__global__ __launch_bounds__(256, 3) void proj_mfma(
    const u16* __restrict__ xbf, const u16* __restrict__ wbf,
    const float* __restrict__ bq, const float* __restrict__ bk, const float* __restrict__ bv,
    u16* __restrict__ qh, u16* __restrict__ kh, u16* __restrict__ vt)
{
    __shared__ __attribute__((aligned(16))) u16 As[128 * 64];
    __shared__ __attribute__((aligned(16))) u16 Bs[128 * 64];

    const int z = blockIdx.z;
    const u16* A = xbf + (size_t)z * 4194304;
    const u16* W = wbf + (size_t)z * 1048576;
    const float* bias = (z == 0) ? bq : (z == 1) ? bk : bv;

    const int tid = threadIdx.x, w = tid >> 6, lane = tid & 63;
    const int quad = lane >> 4, l16 = lane & 15;
    const int m0 = blockIdx.y * 128, n0 = blockIdx.x * 128;
    const int wm = (w & 1) * 64, wn = (w >> 1) * 64;
    const int srow = lane >> 3;                 // 0..7
    const int schunk = (lane & 7) ^ srow;       // xor-swizzled source chunk

    f32x4 acc[4][4];
    #pragma unroll
    for (int mi = 0; mi < 4; ++mi)
        #pragma unroll
        for (int ni = 0; ni < 4; ++ni) acc[mi][ni] = (f32x4){0.f, 0.f, 0.f, 0.f};

    const size_t ar = (size_t)(m0 + 32 * w + srow);
    const size_t br = (size_t)(n0 + 32 * w + srow);

    for (int k0 = 0; k0 < D_; k0 += 64) {
        __syncthreads();
        #pragma unroll
        for (int i = 0; i < 4; ++i) {
            GLOAD_LDS(A + (ar + 8 * i) * D_ + k0 + schunk * 8, &As[(32 * w + 8 * i) * 64]);
            GLOAD_LDS(W + (br + 8 * i) * D_ + k0 + schunk * 8, &Bs[(32 * w + 8 * i) * 64]);
        }
        __syncthreads();

        #pragma unroll
        for (int kg = 0; kg < 2; ++kg) {
            const int ch = ((4 * kg + quad) ^ (l16 & 7)) * 8;
            bf16x8 af[4], bf[4];
            #pragma unroll
            for (int mi = 0; mi < 4; ++mi)
                af[mi] = *(const bf16x8*)&As[(wm + 16 * mi + l16) * 64 + ch];
            #pragma unroll
            for (int ni = 0; ni < 4; ++ni)
                bf[ni] = *(const bf16x8*)&Bs[(wn + 16 * ni + l16) * 64 + ch];
            #pragma unroll
            for (int mi = 0; mi < 4; ++mi)
                #pragma unroll
                for (int ni = 0; ni < 4; ++ni)
                    acc[mi][ni] = MFMA16(af[mi], bf[ni], acc[mi][ni]);
        }
    }

    float bl[4];
    #pragma unroll
    for (int ni = 0; ni < 4; ++ni) bl[ni] = bias[n0 + wn + ni * 16 + l16];

    #pragma unroll
    for (int mi = 0; mi < 4; ++mi) {
        const int mb = m0 + wm + mi * 16 + quad * 4;
        #pragma unroll
        for (int ni = 0; ni < 4; ++ni) {
            const int nn = n0 + wn + ni * 16 + l16;
            const int head = nn >> 6, d = nn & 63;
            if (z < 2) {
                u16* outp = (z == 0) ? qh : kh;
                #pragma unroll
                for (int r = 0; r < 4; ++r) {
                    const int m = mb + r;
                    const int b = m >> 11, t = m & (T_ - 1);
                    outp[((size_t)(head * B_ + b) * T_ + t) * DEPTH + d] =
                        f2bf(acc[mi][ni][r] + bl[ni]);
                }
            } else {
                const int b = mb >> 11, t = mb & (T_ - 1);
                // key permutation: swap bits 2,3 of t (4-aligned run stays a run)
                const int tp = (t & ~12) | ((t & 4) << 1) | ((t & 8) >> 1);
                float4 f = make_float4(acc[mi][ni][0] + bl[ni], acc[mi][ni][1] + bl[ni],
                                       acc[mi][ni][2] + bl[ni], acc[mi][ni][3] + bl[ni]);
                *(uint2*)(vt + ((size_t)(head * B_ + b) * DEPTH + d) * T_ + tp) = pk4(f);
            }
        }
    }
}

// ---------------------------------------------------------------------------
// Flash attention, 32x32 swapped S^T, fixed-max softmax, SPLIT-K over 2 key
// halves. One wave = 32 queries. In-register P: the PV k-slot->key mapping
// key(kc,h,j) = 16kc + 4h + (j&3) + 8(j>>2) makes the S^T output registers
// exactly the PV A-fragments. V's key axis is pre-permuted in proj so each
// PV V-fragment is one b128 chunk (full-bank XOR pattern, same as K reads).
// Schedule (T4): STAGE(next); s_waitcnt vmcnt(4); s_barrier; compute(cur);
// s_barrier -- prefetch stays in flight across the barrier (no vmcnt(0)
// drain per iter). XCD swizzle (T1): each XCD gets 8 consecutive n-groups
// so its K/V working set (2MB) is L2-resident. Mask quirk: row n uses
// mask[n / H].
// ---------------------------------------------------------------------------
__global__ __launch_bounds__(256, 4) void attn_kernel(
    const u16* __restrict__ qh, const u16* __restrict__ kh, const u16* __restrict__ vt,
    const int* __restrict__ maskp, const int* __restrict__ causp,
    u16* __restrict__ po, float* __restrict__ pl)
{
    __shared__ __attribute__((aligned(16))) u16 Ks[2][64 * 64];   // [key][depth] swizzled
    __shared__ __attribute__((aligned(16))) u16 Vs[2][64 * 64];   // [depth][key'] swizzled
    __shared__ __attribute__((aligned(16))) float padf[1024];     // mask*PAD, this half

    // T1: XCD-aware remap (1024 blocks % 8 == 0 -> simple bijective chunking)
    const int lin = blockIdx.x + 16 * blockIdx.y + 512 * blockIdx.z;
    const int swz = (lin & 7) * 128 + (lin >> 3);
    const int qt = swz & 15;            // 128-query tile
    const int n  = (swz >> 4) & 31;     // head*B + b
    const int kk = swz >> 9;            // key half

    const int kbase = kk * 1024;
    const int head = n >> 1, bi = n & 1;
    const int mrow = n >> 4;            // n / H  (reference repeat quirk)
    const int caus = causp[0];

    const int tid  = threadIdx.x;
    const int w    = tid >> 6, lane = tid & 63;
    const int l32  = lane & 31, h = lane >> 5;
    const size_t base  = (size_t)n * T_ * DEPTH;
    const size_t vbase = (size_t)n * DEPTH * T_;
    const size_t elems = (size_t)B_ * T_ * D_;

    const float C1  = 0.18033688011112042f;   // (1/8) * log2(e)
    const float PL2 = -6.2e9f;                // exp2 -> 0

    // precompute pad row for this key half (once per block)
    {
        const int i0 = tid * 4;
        int4 m = *(const int4*)(maskp + (size_t)mrow * T_ + kbase + i0);
        padf[i0 + 0] = (float)m.x * PL2; padf[i0 + 1] = (float)m.y * PL2;
        padf[i0 + 2] = (float)m.z * PL2; padf[i0 + 3] = (float)m.w * PL2;
    }

    // Q fragments (B operand, 32x32x16): lane holds Q[q = l32][c*16 + h*8 + j]
    const int qg = qt * 128 + w * 32 + l32;
    bf16x8 aq[4];
    #pragma unroll
    for (int c = 0; c < 4; ++c)
        aq[c] = *(const bf16x8*)(qh + base + (size_t)qg * DEPTH + c * 16 + h * 8);

    f32x16 O0 = zero16(), O1 = zero16();   // O[q][d], d halves 0..31 / 32..63
    float lp = 0.f;

    // staging addresses: wave w stages tile rows w*16..w*16+15
    const int g_row = w * 16 + (lane >> 3);           // tile row this lane feeds
    const int g_ch  = (lane & 7) ^ ((lane >> 3) & 7); // swizzled source chunk
    const u16* ksrc = kh + base + (size_t)g_row * DEPTH + g_ch * 8;
    const u16* vsrc = vt + vbase + (size_t)g_row * T_ + g_ch * 8;

#define STAGE(bf_, t0_)                                                           \
    do {                                                                          \
        GLOAD_LDS(ksrc + (size_t)(t0_) * DEPTH,       &Ks[bf_][(w * 16) * 64]);   \
        GLOAD_LDS(ksrc + (size_t)((t0_) + 8) * DEPTH, &Ks[bf_][(w * 16 + 8) * 64]); \
        GLOAD_LDS(vsrc + (t0_),                       &Vs[bf_][(w * 16) * 64]);   \
        GLOAD_LDS(vsrc + (size_t)8 * T_ + (t0_),      &Vs[bf_][(w * 16 + 8) * 64]); \
    } while (0)

    STAGE(0, kbase);
    __syncthreads();   // prologue: drains tile-0 loads, covers padf

    for (int it = 0; it < 16; ++it) {
        const int cur = it & 1;
        if (it < 15) {
            STAGE(cur ^ 1, kbase + (it + 1) * 64);  // prefetch flies across barrier
            WAITVM(4);   // own tile-cur loads done (4 newest stay in flight)
        } else {
            WAITVM(0);
        }
        BARRIER();       // all waves' tile-cur data in LDS

        const int lt0 = it * 64;
        bf16x8 pa[2][2];   // [kb][kc] PV A-fragments, built in-register
        #pragma unroll
        for (int kb = 0; kb < 2; ++kb) {
            // S^T = K * Q^T over depth 64: D[key][q], q = l32 (in-lane)
            const int krow = kb * 32 + l32;
            const u16* krp = &Ks[cur][krow * 64];
            const int ksw = krow & 7;
            f32x16 st = zero16();
            #pragma unroll
            for (int c = 0; c < 4; ++c) {
                bf16x8 kf = *(const bf16x8*)(krp + (((c * 2 + h) ^ ksw) * 8));
                st = MFMA32(kf, aq[c], st);
            }
            // softmax: e[r] = exp2(S*C1 + pad), key(r) = (r&3) + 8(r>>2) + 4h
            u32 pk[8];
            #pragma unroll
            for (int g = 0; g < 4; ++g) {
                f32x4 pv = *(const f32x4*)&padf[lt0 + kb * 32 + g * 8 + h * 4];
                #pragma unroll
                for (int m2 = 0; m2 < 2; ++m2) {
                    const int r0 = g * 4 + m2 * 2;
                    float v0 = fmaf(st[r0],     C1, pv[m2 * 2]);
                    float v1 = fmaf(st[r0 + 1], C1, pv[m2 * 2 + 1]);
                    if (caus) {
                        const int kg = kbase + lt0 + kb * 32 + g * 8 + h * 4 + m2 * 2;
                        if (kg     > qg) v0 = PL2;
                        if (kg + 1 > qg) v1 = PL2;
                    }
                    const float e0 = EXP2(v0), e1 = EXP2(v1);
                    lp += e0 + e1;
                    pk[g * 2 + m2] = cvtpk(e0, e1);
                }
            }
            pa[kb][0] = pk_frag(pk[0], pk[1], pk[2], pk[3]);  // e[0..7]
            pa[kb][1] = pk_frag(pk[4], pk[5], pk[6], pk[7]);  // e[8..15]
        }

        // PV: O[q][d] += P * V; V key-permuted so slots (kb,kc,h) = one b128
        #pragma unroll
        for (int dblk = 0; dblk < 2; ++dblk) {
            const int d = dblk * 32 + l32;
            const u16* vrp = &Vs[cur][d * 64];
            const int vsw = d & 7;
            #pragma unroll
            for (int kb = 0; kb < 2; ++kb)
                #pragma unroll
                for (int kc = 0; kc < 2; ++kc) {
                    const int ch = (kb * 4 + kc * 2 + h) ^ vsw;
                    bf16x8 vf = *(const bf16x8*)(vrp + ch * 8);
                    if (dblk == 0) O0 = MFMA32(pa[kb][kc], vf, O0);
                    else           O1 = MFMA32(pa[kb][kc], vf, O1);
                }
        }
        BARRIER();       // compute done before next iter's STAGE overwrites
    }
#undef STAGE

    // fold l across halves; write partial l (query = l32)
    lp += __shfl_xor(lp, 32, 64);
    u16* pop = po + (size_t)kk * elems;
    float* plp = pl + (size_t)kk * 32 * T_;
    if (lane < 32)
        plp[(size_t)n * T_ + qt * 128 + w * 32 + l32] = lp;

    // write partial O (bf16, un-normalized): row r -> query (r&3)+8(r>>2)+4h
    #pragma unroll
    for (int r = 0; r < 16; ++r) {
        const int q = qt * 128 + w * 32 + (r & 3) + 8 * (r >> 2) + 4 * h;
        const size_t rb = ((size_t)bi * T_ + q) * D_ + head * DEPTH + l32;
        pop[rb]      = f2bf(O0[r]);
        pop[rb + 32] = f2bf(O1[r]);
    }
}

// ---------------------------------------------------------------------------
// Fused combine + residual + LayerNorm: x = (po0+po1)/(l0+l1) + q; LN over D.
// ---------------------------------------------------------------------------
__global__ __launch_bounds__(256) void fuse_ln(
    const u16* __restrict__ po, const float* __restrict__ pl,
    const float* __restrict__ qin,
    const float* __restrict__ gamma, const float* __restrict__ beta,
    float* __restrict__ out)
{
    const int row = blockIdx.x;           // bi*T + t
    const int bi = row >> 11, t = row & (T_ - 1);
    const int tid = threadIdx.x;
    const size_t elems = (size_t)B_ * T_ * D_;

    const int head = tid >> 4;
    const size_t li = (size_t)(head * B_ + bi) * T_ + t;
    const float l = pl[li] + pl[32 * T_ + li];
    const float inv = 1.0f / fmaxf(l, 1e-30f);

    const size_t basei = (size_t)row * D_ + (tid << 2);
    uint2 a = *(const uint2*)(po + basei);
    uint2 b = *(const uint2*)(po + elems + basei);
    float4 qv = *(const float4*)(qin + basei);
    float x[4];
    x[0] = (bf2f(a.x & 0xffffu) + bf2f(b.x & 0xffffu)) * inv + qv.x;
    x[1] = (bf2f(a.x >> 16)     + bf2f(b.x >> 16))     * inv + qv.y;
    x[2] = (bf2f(a.y & 0xffffu) + bf2f(b.y & 0xffffu)) * inv + qv.z;
    x[3] = (bf2f(a.y >> 16)     + bf2f(b.y >> 16))     * inv + qv.w;

    float s  = x[0] + x[1] + x[2] + x[3];
    float s2 = x[0]*x[0] + x[1]*x[1] + x[2]*x[2] + x[3]*x[3];
    #pragma unroll
    for (int off = 1; off < 64; off <<= 1) {
        s  += __shfl_xor(s, off, 64);
        s2 += __shfl_xor(s2, off, 64);
    }
    __shared__ float rs[4], rs2[4];
    const int wid = tid >> 6;
    if ((tid & 63) == 0) { rs[wid] = s; rs2[wid] = s2; }
    __syncthreads();
    s  = rs[0] + rs[1] + rs[2] + rs[3];
    s2 = rs2[0] + rs2[1] + rs2[2] + rs2[3];
    const float mean = s * (1.0f / (float)D_);
    const float var  = s2 * (1.0f / (float)D_) - mean * mean;
    const float rstd = rsqrtf(var + 1e-5f);
    float4 g = *(const float4*)(gamma + (tid << 2));
    float4 bb = *(const float4*)(beta + (tid << 2));
    float4 r;
    r.x = (x[0] - mean) * rstd * g.x + bb.x;
    r.y = (x[1] - mean) * rstd * g.y + bb.y;
    r.z = (x[2] - mean) * rstd * g.z + bb.z;
    r.w = (x[3] - mean) * rstd * g.w + bb.w;
    *(float4*)(out + basei) = r;
}

extern "C" void kernel_launch(void* const* d_in, const int* in_sizes, int n_in,
                              void* d_out, int out_size, void* d_ws, size_t ws_size,
                              hipStream_t stream)
{
    (void)in_sizes; (void)n_in; (void)out_size; (void)ws_size;
    const float* q    = (const float*)d_in[0];
    const float* k    = (const float*)d_in[1];
    const float* v    = (const float*)d_in[2];
    const int* mask = (const int*)d_in[3];
    const int* caus = (const int*)d_in[4];
    /* d_in[5] = edge_fea (unused) */
    const float* wq = (const float*)d_in[6];
    const float* bq = (const float*)d_in[7];
    const float* wk = (const float*)d_in[8];
    const float* bk = (const float*)d_in[9];
    const float* wv = (const float*)d_in[10];
    const float* bv = (const float*)d_in[11];
    const float* gamma = (const float*)d_in[12];
    const float* beta  = (const float*)d_in[13];
    float* out = (float*)d_out;

    const size_t elems = (size_t)B_ * T_ * D_;   // 4,194,304
    u16* qh  = (u16*)d_ws;
    u16* kh  = qh + elems;
    u16* vt  = kh + elems;                       // transposed V [n][64][T'] (key-permuted)
    u16* xbf = vt + elems;                       // bf16 X, 3 tensors (dead after proj)
    u16* wbf = xbf + 3 * elems;                  // bf16 W, 3 tensors
    // po/pl reuse the xbf region (proj finished before attn writes them):
    u16* po   = xbf;                             // 2 x elems bf16 partial O
    float* pl = (float*)(po + 2 * elems);        // 2 x 32 x T fp32 partial l

    conv_kernel<<<dim3(512, 6), 256, 0, stream>>>(q, k, v, wq, wk, wv, xbf, wbf);
    proj_mfma<<<dim3(8, 32, 3), 256, 0, stream>>>(xbf, wbf, bq, bk, bv, qh, kh, vt);

    dim3 agrid(T_ / 128, H_ * B_, 2);            // 16 x 32 x 2 = 1024 blocks
    attn_kernel<<<agrid, 256, 0, stream>>>(qh, kh, vt, mask, caus, po, pl);

    fuse_ln<<<B_ * T_, 256, 0, stream>>>(po, pl, q, gamma, beta, out);
}

// Round 4
// 209.972 us; speedup vs baseline: 1.0496x; 1.0221x over previous
//
#include <hip/hip_runtime.h>
#include <hip/hip_bf16.h>
#include <stdint.h>

#define B_ 2
#define T_ 2048
#define D_ 1024
#define H_ 16
#define DEPTH 64

typedef unsigned short u16;
typedef unsigned int u32;
typedef short bf16x8 __attribute__((ext_vector_type(8)));
typedef float f32x4 __attribute__((ext_vector_type(4)));
typedef float f32x16 __attribute__((ext_vector_type(16)));

#define MFMA16(a, b, c) __builtin_amdgcn_mfma_f32_16x16x32_bf16(a, b, c, 0, 0, 0)
#define MFMA32(a, b, c) __builtin_amdgcn_mfma_f32_32x32x16_bf16(a, b, c, 0, 0, 0)

// raw v_exp_f32 (1 VALU inst) -- OCML exp2f costs ~10+ insts in fixups we
// don't need (args in [-6.2e9, ~2]; result rounded to bf16 afterwards anyway)
#if __has_builtin(__builtin_amdgcn_exp2f)
#define EXP2(x) __builtin_amdgcn_exp2f(x)
#else
#define EXP2(x) __expf((x) * 0.6931471805599453f)
#endif

// async global->LDS, 16B per lane; LDS dest = wave-uniform base + lane*16
#define GLOAD_LDS(g, l)                                                      \
    __builtin_amdgcn_global_load_lds(                                        \
        (__attribute__((address_space(1))) void*)(g),                        \
        (__attribute__((address_space(3))) void*)(l), 16, 0, 0)

// counted waits / raw barrier with compiler memory fences (T4)
#define WAITVM(n) asm volatile("s_waitcnt vmcnt(" #n ")" ::: "memory")
#define BARRIER()                                                            \
    do {                                                                     \
        asm volatile("" ::: "memory");                                       \
        __builtin_amdgcn_s_barrier();                                        \
        asm volatile("" ::: "memory");                                       \
    } while (0)

__device__ __forceinline__ float bf2f(u32 u) {
    union { u32 i; float f; } x; x.i = u << 16; return x.f;
}
__device__ __forceinline__ u16 f2bf(float f) {
    union { float f; u32 i; } x; x.f = f;
    u32 r = x.i + 0x7fffu + ((x.i >> 16) & 1u);
    return (u16)(r >> 16);
}
__device__ __forceinline__ uint2 pk4(float4 f) {
    return make_uint2((u32)f2bf(f.x) | ((u32)f2bf(f.y) << 16),
                      (u32)f2bf(f.z) | ((u32)f2bf(f.w) << 16));
}
// 1-inst packed f32->bf16x2 (RNE); compiler cannot derive this from bit-ops
__device__ __forceinline__ u32 cvtpk(float lo, float hi) {
    u32 r;
    asm("v_cvt_pk_bf16_f32 %0, %1, %2" : "=v"(r) : "v"(lo), "v"(hi));
    return r;
}
__device__ __forceinline__ bf16x8 pk_frag(u32 a, u32 b, u32 c, u32 d) {
    union { u32 u[4]; bf16x8 v; } x;
    x.u[0] = a; x.u[1] = b; x.u[2] = c; x.u[3] = d;
    return x.v;
}
__device__ __forceinline__ f32x16 zero16() {
    f32x16 z;
    #pragma unroll
    for (int i = 0; i < 16; ++i) z[i] = 0.f;
    return z;
}

// ---------------------------------------------------------------------------
// fp32 -> bf16 convert: X (q,k,v: 4M each) and W (wq,wk,wv: 1M each)
// ---------------------------------------------------------------------------
__global__ __launch_bounds__(256) void conv_kernel(
    const float* __restrict__ s0, const float* __restrict__ s1, const float* __restrict__ s2,
    const float* __restrict__ s3, const float* __restrict__ s4, const float* __restrict__ s5,
    u16* __restrict__ xbf, u16* __restrict__ wbf)
{
    const int z = blockIdx.y;
    const float* src = (z == 0) ? s0 : (z == 1) ? s1 : (z == 2) ? s2
                     : (z == 3) ? s3 : (z == 4) ? s4 : s5;
    u16* dst = (z < 3) ? (xbf + (size_t)z * 4194304) : (wbf + (size_t)(z - 3) * 1048576);
    const size_t nel = (z < 3) ? 4194304u : 1048576u;
    for (size_t i = ((size_t)blockIdx.x * 256 + threadIdx.x) * 8; i < nel;
         i += (size_t)gridDim.x * 2048) {
        float4 a = *(const float4*)(src + i);
        float4 b = *(const float4*)(src + i + 4);
        uint2 lo = pk4(a), hi = pk4(b);
        *(uint4*)(dst + i) = make_uint4(lo.x, lo.y, hi.x, hi.y);
    }
}

// ---------------------------------------------------------------------------
// Projection: bf16 X @ W^T + bias. 128x128 tile, BK=64, global_load_lds
// width-16, XOR chunk swizzle, single-buffered. Epilogue routes the 128x128
// acc tile through LDS (reusing the staging buffer, stride-132 pad) so ALL
// global stores are coalesced 8B runs:
//   z<2 : Q/K head-split [h*B+b][t][64] -- rows of 64 d contiguous
//   z==2: V transposed [h*B+b][64][T'] (key bit2<->bit3 permuted within 16,
//         applied at the LDS write) -- rows of 128 t contiguous
// Previous epilogue stored V at 4KB stride (4B/line, ~16x write
// amplification + L2 RMW fills); this removes it.
// ---------------------------------------------------------------------------
__global__ __launch_bounds__(256, 3) void proj_mfma(
    const u16* __restrict__ xbf, const u16* __restrict__ wbf,
    const float* __restrict__ bq, const float* __restrict__ bk, const float* __restrict__ bv,
    u16* __restrict__ qh, u16* __restrict__ kh, u16* __restrict__ vt)
{
    // staging (As = SH[0..8191], Bs = SH[8192..16383]) and epilogue transpose
    // tile (128 x 132 u16) share one allocation.
    __shared__ __attribute__((aligned(16))) u16 SH[128 * 132];
    u16* As = SH;
    u16* Bs = SH + 8192;

    const int z = blockIdx.z;
    const u16* A = xbf + (size_t)z * 4194304;
    const u16* W = wbf + (size_t)z * 1048576;
    const float* bias = (z == 0) ? bq : (z == 1) ? bk : bv;

    const int tid = threadIdx.x, w = tid >> 6, lane = tid & 63;
    const int quad = lane >> 4, l16 = lane & 15;
    const int m0 = blockIdx.y * 128, n0 = blockIdx.x * 128;
    const int wm = (w & 1) * 64, wn = (w >> 1) * 64;
    const int srow = lane >> 3;                 // 0..7
    const int schunk = (lane & 7) ^ srow;       // xor-swizzled source chunk

    f32x4 acc[4][4];
    #pragma unroll
    for (int mi = 0; mi < 4; ++mi)
        #pragma unroll
        for (int ni = 0; ni < 4; ++ni) acc[mi][ni] = (f32x4){0.f, 0.f, 0.f, 0.f};

    const size_t ar = (size_t)(m0 + 32 * w + srow);
    const size_t br = (size_t)(n0 + 32 * w + srow);

    for (int k0 = 0; k0 < D_; k0 += 64) {
        __syncthreads();
        #pragma unroll
        for (int i = 0; i < 4; ++i) {
            GLOAD_LDS(A + (ar + 8 * i) * D_ + k0 + schunk * 8, &As[(32 * w + 8 * i) * 64]);
            GLOAD_LDS(W + (br + 8 * i) * D_ + k0 + schunk * 8, &Bs[(32 * w + 8 * i) * 64]);
        }
        __syncthreads();

        #pragma unroll
        for (int kg = 0; kg < 2; ++kg) {
            const int ch = ((4 * kg + quad) ^ (l16 & 7)) * 8;
            bf16x8 af[4], bf[4];
            #pragma unroll
            for (int mi = 0; mi < 4; ++mi)
                af[mi] = *(const bf16x8*)&As[(wm + 16 * mi + l16) * 64 + ch];
            #pragma unroll
            for (int ni = 0; ni < 4; ++ni)
                bf[ni] = *(const bf16x8*)&Bs[(wn + 16 * ni + l16) * 64 + ch];
            #pragma unroll
            for (int mi = 0; mi < 4; ++mi)
                #pragma unroll
                for (int ni = 0; ni < 4; ++ni)
                    acc[mi][ni] = MFMA16(af[mi], bf[ni], acc[mi][ni]);
        }
    }

    float bl[4];
    #pragma unroll
    for (int ni = 0; ni < 4; ++ni) bl[ni] = bias[n0 + wn + ni * 16 + l16];

    __syncthreads();   // all waves done reading As/Bs; SH becomes epilogue tile

    if (z < 2) {
        // LDS as [t_loc][nn], stride 132 (banks: 2(t)+nn/2 -> full coverage)
        #pragma unroll
        for (int mi = 0; mi < 4; ++mi) {
            #pragma unroll
            for (int ni = 0; ni < 4; ++ni) {
                const int nn = wn + ni * 16 + l16;
                #pragma unroll
                for (int r = 0; r < 4; ++r) {
                    const int tl = wm + mi * 16 + quad * 4 + r;
                    SH[tl * 132 + nn] = f2bf(acc[mi][ni][r] + bl[ni]);
                }
            }
        }
    } else {
        // LDS as [nn][tp], stride 132; 4-run of t packs into one uint2;
        // key permutation (swap bits 2,3 of t) applied to the column index
        #pragma unroll
        for (int mi = 0; mi < 4; ++mi) {
            const int t4 = wm + mi * 16 + quad * 4;
            const int tp4 = (t4 & ~12) | ((t4 & 4) << 1) | ((t4 & 8) >> 1);
            #pragma unroll
            for (int ni = 0; ni < 4; ++ni) {
                const int nn = wn + ni * 16 + l16;
                float4 f = make_float4(acc[mi][ni][0] + bl[ni], acc[mi][ni][1] + bl[ni],
                                       acc[mi][ni][2] + bl[ni], acc[mi][ni][3] + bl[ni]);
                *(uint2*)&SH[nn * 132 + tp4] = pk4(f);
            }
        }
    }
    __syncthreads();

    // coalesced store: 32 lanes sweep one 128-u16 LDS row, 8B per lane
    {
        const int ch = tid & 31;          // 8B chunk within the row
        const int r0 = tid >> 5;          // row 0..7 (+8 per sweep)
        const int b  = m0 >> 11;          // batch, constant per block
        const int tb = m0 & (T_ - 1);
        if (z < 2) {
            u16* outp = (z == 0) ? qh : kh;
            const int hd = ch >> 4;            // which head-half of the row
            const int head = (n0 >> 6) + hd;
            const int dd = (ch & 15) * 4;      // d offset (4 u16)
            #pragma unroll
            for (int s = 0; s < 16; ++s) {
                const int tl = r0 + s * 8;
                uint2 vv = *(const uint2*)&SH[tl * 132 + hd * 64 + dd];
                *(uint2*)(outp + ((size_t)(head * B_ + b) * T_ + tb + tl) * DEPTH + dd) = vv;
            }
        } else {
            #pragma unroll
            for (int s = 0; s < 16; ++s) {
                const int nn = r0 + s * 8;
                const int nng = n0 + nn;
                const int head = nng >> 6, d = nng & 63;
                uint2 vv = *(const uint2*)&SH[nn * 132 + ch * 4];
                *(uint2*)(vt + ((size_t)(head * B_ + b) * DEPTH + d) * T_ + tb + ch * 4) = vv;
            }
        }
    }
}

// ---------------------------------------------------------------------------
// Flash attention, 32x32 swapped S^T, fixed-max softmax, SPLIT-K over 2 key
// halves. One wave = 32 queries. In-register P: the PV k-slot->key mapping
// key(kc,h,j) = 16kc + 4h + (j&3) + 8(j>>2) makes the S^T output registers
// exactly the PV A-fragments. V's key axis is pre-permuted in proj so each
// PV V-fragment is one b128 chunk (full-bank XOR pattern, same as K reads).
// Schedule (T4): STAGE(next); s_waitcnt vmcnt(4); s_barrier; compute(cur);
// s_barrier -- prefetch stays in flight across the barrier (no vmcnt(0)
// drain per iter). XCD swizzle (T1): each XCD gets 8 consecutive n-groups
// so its K/V working set (2MB) is L2-resident. Mask quirk: row n uses
// mask[n / H].
// ---------------------------------------------------------------------------
__global__ __launch_bounds__(256, 4) void attn_kernel(
    const u16* __restrict__ qh, const u16* __restrict__ kh, const u16* __restrict__ vt,
    const int* __restrict__ maskp, const int* __restrict__ causp,
    u16* __restrict__ po, float* __restrict__ pl)
{
    __shared__ __attribute__((aligned(16))) u16 Ks[2][64 * 64];   // [key][depth] swizzled
    __shared__ __attribute__((aligned(16))) u16 Vs[2][64 * 64];   // [depth][key'] swizzled
    __shared__ __attribute__((aligned(16))) float padf[1024];     // mask*PAD, this half

    // T1: XCD-aware remap (1024 blocks % 8 == 0 -> simple bijective chunking)
    const int lin = blockIdx.x + 16 * blockIdx.y + 512 * blockIdx.z;
    const int swz = (lin & 7) * 128 + (lin >> 3);
    const int qt = swz & 15;            // 128-query tile
    const int n  = (swz >> 4) & 31;     // head*B + b
    const int kk = swz >> 9;            // key half

    const int kbase = kk * 1024;
    const int head = n >> 1, bi = n & 1;
    const int mrow = n >> 4;            // n / H  (reference repeat quirk)
    const int caus = causp[0];

    const int tid  = threadIdx.x;
    const int w    = tid >> 6, lane = tid & 63;
    const int l32  = lane & 31, h = lane >> 5;
    const size_t base  = (size_t)n * T_ * DEPTH;
    const size_t vbase = (size_t)n * DEPTH * T_;
    const size_t elems = (size_t)B_ * T_ * D_;

    const float C1  = 0.18033688011112042f;   // (1/8) * log2(e)
    const float PL2 = -6.2e9f;                // exp2 -> 0

    // precompute pad row for this key half (once per block)
    {
        const int i0 = tid * 4;
        int4 m = *(const int4*)(maskp + (size_t)mrow * T_ + kbase + i0);
        padf[i0 + 0] = (float)m.x * PL2; padf[i0 + 1] = (float)m.y * PL2;
        padf[i0 + 2] = (float)m.z * PL2; padf[i0 + 3] = (float)m.w * PL2;
    }

    // Q fragments (B operand, 32x32x16): lane holds Q[q = l32][c*16 + h*8 + j]
    const int qg = qt * 128 + w * 32 + l32;
    bf16x8 aq[4];
    #pragma unroll
    for (int c = 0; c < 4; ++c)
        aq[c] = *(const bf16x8*)(qh + base + (size_t)qg * DEPTH + c * 16 + h * 8);

    f32x16 O0 = zero16(), O1 = zero16();   // O[q][d], d halves 0..31 / 32..63
    float lp = 0.f;

    // staging addresses: wave w stages tile rows w*16..w*16+15
    const int g_row = w * 16 + (lane >> 3);           // tile row this lane feeds
    const int g_ch  = (lane & 7) ^ ((lane >> 3) & 7); // swizzled source chunk
    const u16* ksrc = kh + base + (size_t)g_row * DEPTH + g_ch * 8;
    const u16* vsrc = vt + vbase + (size_t)g_row * T_ + g_ch * 8;

#define STAGE(bf_, t0_)                                                           \
    do {                                                                          \
        GLOAD_LDS(ksrc + (size_t)(t0_) * DEPTH,       &Ks[bf_][(w * 16) * 64]);   \
        GLOAD_LDS(ksrc + (size_t)((t0_) + 8) * DEPTH, &Ks[bf_][(w * 16 + 8) * 64]); \
        GLOAD_LDS(vsrc + (t0_),                       &Vs[bf_][(w * 16) * 64]);   \
        GLOAD_LDS(vsrc + (size_t)8 * T_ + (t0_),      &Vs[bf_][(w * 16 + 8) * 64]); \
    } while (0)

    STAGE(0, kbase);
    __syncthreads();   // prologue: drains tile-0 loads, covers padf

    for (int it = 0; it < 16; ++it) {
        const int cur = it & 1;
        if (it < 15) {
            STAGE(cur ^ 1, kbase + (it + 1) * 64);  // prefetch flies across barrier
            WAITVM(4);   // own tile-cur loads done (4 newest stay in flight)
        } else {
            WAITVM(0);
        }
        BARRIER();       // all waves' tile-cur data in LDS

        const int lt0 = it * 64;
        bf16x8 pa[2][2];   // [kb][kc] PV A-fragments, built in-register
        #pragma unroll
        for (int kb = 0; kb < 2; ++kb) {
            // S^T = K * Q^T over depth 64: D[key][q], q = l32 (in-lane)
            const int krow = kb * 32 + l32;
            const u16* krp = &Ks[cur][krow * 64];
            const int ksw = krow & 7;
            f32x16 st = zero16();
            #pragma unroll
            for (int c = 0; c < 4; ++c) {
                bf16x8 kf = *(const bf16x8*)(krp + (((c * 2 + h) ^ ksw) * 8));
                st = MFMA32(kf, aq[c], st);
            }
            // softmax: e[r] = exp2(S*C1 + pad), key(r) = (r&3) + 8(r>>2) + 4h
            u32 pk[8];
            #pragma unroll
            for (int g = 0; g < 4; ++g) {
                f32x4 pv = *(const f32x4*)&padf[lt0 + kb * 32 + g * 8 + h * 4];
                #pragma unroll
                for (int m2 = 0; m2 < 2; ++m2) {
                    const int r0 = g * 4 + m2 * 2;
                    float v0 = fmaf(st[r0],     C1, pv[m2 * 2]);
                    float v1 = fmaf(st[r0 + 1], C1, pv[m2 * 2 + 1]);
                    if (caus) {
                        const int kg = kbase + lt0 + kb * 32 + g * 8 + h * 4 + m2 * 2;
                        if (kg     > qg) v0 = PL2;
                        if (kg + 1 > qg) v1 = PL2;
                    }
                    const float e0 = EXP2(v0), e1 = EXP2(v1);
                    lp += e0 + e1;
                    pk[g * 2 + m2] = cvtpk(e0, e1);
                }
            }
            pa[kb][0] = pk_frag(pk[0], pk[1], pk[2], pk[3]);  // e[0..7]
            pa[kb][1] = pk_frag(pk[4], pk[5], pk[6], pk[7]);  // e[8..15]
        }

        // PV: O[q][d] += P * V; V key-permuted so slots (kb,kc,h) = one b128
        #pragma unroll
        for (int dblk = 0; dblk < 2; ++dblk) {
            const int d = dblk * 32 + l32;
            const u16* vrp = &Vs[cur][d * 64];
            const int vsw = d & 7;
            #pragma unroll
            for (int kb = 0; kb < 2; ++kb)
                #pragma unroll
                for (int kc = 0; kc < 2; ++kc) {
                    const int ch = (kb * 4 + kc * 2 + h) ^ vsw;
                    bf16x8 vf = *(const bf16x8*)(vrp + ch * 8);
                    if (dblk == 0) O0 = MFMA32(pa[kb][kc], vf, O0);
                    else           O1 = MFMA32(pa[kb][kc], vf, O1);
                }
        }
        BARRIER();       // compute done before next iter's STAGE overwrites
    }
#undef STAGE

    // fold l across halves; write partial l (query = l32)
    lp += __shfl_xor(lp, 32, 64);
    u16* pop = po + (size_t)kk * elems;
    float* plp = pl + (size_t)kk * 32 * T_;
    if (lane < 32)
        plp[(size_t)n * T_ + qt * 128 + w * 32 + l32] = lp;

    // write partial O (bf16, un-normalized): row r -> query (r&3)+8(r>>2)+4h
    #pragma unroll
    for (int r = 0; r < 16; ++r) {
        const int q = qt * 128 + w * 32 + (r & 3) + 8 * (r >> 2) + 4 * h;
        const size_t rb = ((size_t)bi * T_ + q) * D_ + head * DEPTH + l32;
        pop[rb]      = f2bf(O0[r]);
        pop[rb + 32] = f2bf(O1[r]);
    }
}

// ---------------------------------------------------------------------------
// Fused combine + residual + LayerNorm: x = (po0+po1)/(l0+l1) + q; LN over D.
// ---------------------------------------------------------------------------
__global__ __launch_bounds__(256) void fuse_ln(
    const u16* __restrict__ po, const float* __restrict__ pl,
    const float* __restrict__ qin,
    const float* __restrict__ gamma, const float* __restrict__ beta,
    float* __restrict__ out)
{
    const int row = blockIdx.x;           // bi*T + t
    const int bi = row >> 11, t = row & (T_ - 1);
    const int tid = threadIdx.x;
    const size_t elems = (size_t)B_ * T_ * D_;

    const int head = tid >> 4;
    const size_t li = (size_t)(head * B_ + bi) * T_ + t;
    const float l = pl[li] + pl[32 * T_ + li];
    const float inv = 1.0f / fmaxf(l, 1e-30f);

    const size_t basei = (size_t)row * D_ + (tid << 2);
    uint2 a = *(const uint2*)(po + basei);
    uint2 b = *(const uint2*)(po + elems + basei);
    float4 qv = *(const float4*)(qin + basei);
    float x[4];
    x[0] = (bf2f(a.x & 0xffffu) + bf2f(b.x & 0xffffu)) * inv + qv.x;
    x[1] = (bf2f(a.x >> 16)     + bf2f(b.x >> 16))     * inv + qv.y;
    x[2] = (bf2f(a.y & 0xffffu) + bf2f(b.y & 0xffffu)) * inv + qv.z;
    x[3] = (bf2f(a.y >> 16)     + bf2f(b.y >> 16))     * inv + qv.w;

    float s  = x[0] + x[1] + x[2] + x[3];
    float s2 = x[0]*x[0] + x[1]*x[1] + x[2]*x[2] + x[3]*x[3];
    #pragma unroll
    for (int off = 1; off < 64; off <<= 1) {
        s  += __shfl_xor(s, off, 64);
        s2 += __shfl_xor(s2, off, 64);
    }
    __shared__ float rs[4], rs2[4];
    const int wid = tid >> 6;
    if ((tid & 63) == 0) { rs[wid] = s; rs2[wid] = s2; }
    __syncthreads();
    s  = rs[0] + rs[1] + rs[2] + rs[3];
    s2 = rs2[0] + rs2[1] + rs2[2] + rs2[3];
    const float mean = s * (1.0f / (float)D_);
    const float var  = s2 * (1.0f / (float)D_) - mean * mean;
    const float rstd = rsqrtf(var + 1e-5f);
    float4 g = *(const float4*)(gamma + (tid << 2));
    float4 bb = *(const float4*)(beta + (tid << 2));
    float4 r;
    r.x = (x[0] - mean) * rstd * g.x + bb.x;
    r.y = (x[1] - mean) * rstd * g.y + bb.y;
    r.z = (x[2] - mean) * rstd * g.z + bb.z;
    r.w = (x[3] - mean) * rstd * g.w + bb.w;
    *(float4*)(out + basei) = r;
}

extern "C" void kernel_launch(void* const* d_in, const int* in_sizes, int n_in,
                              void* d_out, int out_size, void* d_ws, size_t ws_size,
                              hipStream_t stream)
{
    (void)in_sizes; (void)n_in; (void)out_size; (void)ws_size;
    const float* q    = (const float*)d_in[0];
    const float* k    = (const float*)d_in[1];
    const float* v    = (const float*)d_in[2];
    const int* mask = (const int*)d_in[3];
    const int* caus = (const int*)d_in[4];
    /* d_in[5] = edge_fea (unused) */
    const float* wq = (const float*)d_in[6];
    const float* bq = (const float*)d_in[7];
    const float* wk = (const float*)d_in[8];
    const float* bk = (const float*)d_in[9];
    const float* wv = (const float*)d_in[10];
    const float* bv = (const float*)d_in[11];
    const float* gamma = (const float*)d_in[12];
    const float* beta  = (const float*)d_in[13];
    float* out = (float*)d_out;

    const size_t elems = (size_t)B_ * T_ * D_;   // 4,194,304
    u16* qh  = (u16*)d_ws;
    u16* kh  = qh + elems;
    u16* vt  = kh + elems;                       // transposed V [n][64][T'] (key-permuted)
    u16* xbf = vt + elems;                       // bf16 X, 3 tensors (dead after proj)
    u16* wbf = xbf + 3 * elems;                  // bf16 W, 3 tensors
    // po/pl reuse the xbf region (proj finished before attn writes them):
    u16* po   = xbf;                             // 2 x elems bf16 partial O
    float* pl = (float*)(po + 2 * elems);        // 2 x 32 x T fp32 partial l

    conv_kernel<<<dim3(512, 6), 256, 0, stream>>>(q, k, v, wq, wk, wv, xbf, wbf);
    proj_mfma<<<dim3(8, 32, 3), 256, 0, stream>>>(xbf, wbf, bq, bk, bv, qh, kh, vt);

    dim3 agrid(T_ / 128, H_ * B_, 2);            // 16 x 32 x 2 = 1024 blocks
    attn_kernel<<<agrid, 256, 0, stream>>>(qh, kh, vt, mask, caus, po, pl);

    fuse_ln<<<B_ * T_, 256, 0, stream>>>(po, pl, q, gamma, beta, out);
}